// Round 6
// baseline (200.934 us; speedup 1.0000x reference)
//
#include <hip/hip_runtime.h>

// Problem constants (from reference): B=16384, D=255, K=4, L=16, T=1020
constexpr int T_TUN = 1020;
constexpr int D_DST = 255;
constexpr int L_LNK = 16;
constexpr float EPS = 1e-8f;
constexpr int ROWS_PER_BLOCK = 8;   // 4 waves x 2 rows (float2-packed)

__device__ __forceinline__ float read_lane_f(float v, int l) {
  return __builtin_bit_cast(float,
      __builtin_amdgcn_readlane(__builtin_bit_cast(int, v), l));
}

__global__ __launch_bounds__(256) void rowloss_kernel(
    const float* __restrict__ pred,     // [B, T]
    const float* __restrict__ demands,  // [B, D]
    const float* __restrict__ cur,      // [B, L]
    const float* __restrict__ caps,     // [L]
    const int*   __restrict__ t2l,      // [T]
    float* __restrict__ out, float invB)
{
  const int tid  = threadIdx.x;
  const int lane = tid & 63;
  const int w    = tid >> 6;   // wave id 0..3

  // float2 bin cell packs BOTH rows: one b64 RMW updates 2 rows.
  // dword addr = bin*128 + lane*2 -> 4 dwords/bank exactly (conflict-free b64).
  __shared__ float2 bins_all[4][L_LNK][64];   // 8 KB/wave, 32 KB/block
  float2 (*binsw)[64] = bins_all[w];

  const int b16 = lane & 15;       // this lane's bin for the reduce/stats
  const int g   = lane >> 4;       // lane group 0..3
  const float capinv = 1.0f / (caps[b16] + EPS);

  // Row-invariant scatter cell indices (flattened [bin][copy] -> bin*64+lane)
  int off[4][4];
  bool dv[4];
#pragma unroll
  for (int j = 0; j < 4; ++j) {
    const int d = lane + 64 * j;
    dv[j] = (d < D_DST);
    const int dd = dv[j] ? d : 0;
    const int4 lk = ((const int4*)t2l)[dd];   // t2l[4d..4d+3]
    off[j][0] = lk.x * 64 + lane;
    off[j][1] = lk.y * 64 + lane;
    off[j][2] = lk.z * 64 + lane;
    off[j][3] = lk.w * 64 + lane;
  }

  const int row0 = blockIdx.x * ROWS_PER_BLOCK + w * 2;

  // ---- issue ALL global loads for both rows up front (max MLP) ----
  float4 r4[2][4];
  float  dm[2][4];
  float  mycur[2];
#pragma unroll
  for (int r = 0; r < 2; ++r) {
    const int b = row0 + r;
    const float4* prow = (const float4*)(pred + (size_t)b * T_TUN);
    const float*  drow = demands + (size_t)b * D_DST;
    mycur[r] = cur[(size_t)b * L_LNK + b16];
#pragma unroll
    for (int j = 0; j < 4; ++j) {
      const int d = lane + 64 * j;
      if (dv[j]) { r4[r][j] = prow[d]; dm[r][j] = drow[d]; }
    }
  }

  // ---- zero the wave's 2048-float region: 8x ds_write_b128 ----
  {
    const float4 z = make_float4(0.f, 0.f, 0.f, 0.f);
    float4* pz = (float4*)binsw;
#pragma unroll
    for (int i = 0; i < 8; ++i) pz[lane + 64 * i] = z;
  }

  // ---- scatter: one b64 RMW covers both rows ----
  float2* cells = (float2*)binsw;
#pragma unroll
  for (int j = 0; j < 4; ++j) {
    if (!dv[j]) continue;            // only lane63/j3 diverges
#pragma unroll
    for (int c = 0; c < 4; ++c) {
      const float rx = (c == 0) ? r4[0][j].x : (c == 1) ? r4[0][j].y
                     : (c == 2) ? r4[0][j].z : r4[0][j].w;
      const float ry = (c == 0) ? r4[1][j].x : (c == 1) ? r4[1][j].y
                     : (c == 2) ? r4[1][j].z : r4[1][j].w;
      float2 v = cells[off[j][c]];
      v.x += rx * dm[0][j];
      v.y += ry * dm[1][j];
      cells[off[j][c]] = v;
    }
  }

  // ---- column reduce: 16 b64 reads (rotated copy walk), then fold groups ----
  float csx = 0.0f, csy = 0.0f;
#pragma unroll
  for (int k = 0; k < 16; ++k) {
    const int copy = 16 * g + ((k + b16) & 15);
    const float2 v = binsw[b16][copy];
    csx += v.x; csy += v.y;
  }
  csx += __shfl_xor(csx, 16, 64); csx += __shfl_xor(csx, 32, 64);
  csy += __shfl_xor(csy, 16, 64); csy += __shfl_xor(csy, 32, 64);

  // ---- fused stats: group 0 sums u, 1 sums u^2, 2 sums u*cur, 3 maxes u ----
  float val[2];
  {
    const float u0 = csx * capinv;
    const float u1 = csy * capinv;
    val[0] = (g == 0) ? u0 : (g == 1) ? (u0 * u0) : (g == 2) ? (u0 * mycur[0]) : u0;
    val[1] = (g == 0) ? u1 : (g == 1) ? (u1 * u1) : (g == 2) ? (u1 * mycur[1]) : u1;
  }
#pragma unroll
  for (int m = 1; m < 16; m <<= 1) {
#pragma unroll
    for (int r = 0; r < 2; ++r) {
      const float o  = __shfl_xor(val[r], m, 64);
      const float sm = val[r] + o;
      const float mm = fmaxf(val[r], o);
      val[r] = (g == 3) ? mm : sm;
    }
  }

  float acc = 0.0f;
#pragma unroll
  for (int r = 0; r < 2; ++r) {
    const float s1 = read_lane_f(val[r], 0);
    const float s2 = read_lane_f(val[r], 16);
    const float s3 = read_lane_f(val[r], 32);
    const float mx = read_lane_f(val[r], 48);
    const float var = (s2 - s1 * s1 * (1.0f / 16.0f)) * (1.0f / 15.0f); // ddof=1
    acc += 0.3f * var + 0.5f * s3 + 0.2f * mx;
  }

  // one global atomic per wave (8192 total) — no wacc, no __syncthreads
  if (lane == 0) atomicAdd(out, acc * invB);
}

__global__ void zero_out_kernel(float* __restrict__ out) { out[0] = 0.0f; }

extern "C" void kernel_launch(void* const* d_in, const int* in_sizes, int n_in,
                              void* d_out, int out_size, void* d_ws, size_t ws_size,
                              hipStream_t stream) {
  const float* pred    = (const float*)d_in[0];  // [B, T]
  const float* demands = (const float*)d_in[1];  // [B, D]
  const float* cur     = (const float*)d_in[2];  // [B, L]
  const float* caps    = (const float*)d_in[3];  // [L]
  const int*   t2l     = (const int*)d_in[4];    // [T]
  float* out = (float*)d_out;

  const int L = in_sizes[3];          // 16
  const int B = in_sizes[2] / L;      // 16384

  const int grid = B / ROWS_PER_BLOCK;  // 2048

  zero_out_kernel<<<1, 1, 0, stream>>>(out);
  rowloss_kernel<<<grid, 256, 0, stream>>>(pred, demands, cur, caps, t2l,
                                           out, 1.0f / (float)B);
}

// Round 7
// 109.189 us; speedup vs baseline: 1.8402x; 1.8402x over previous
//
#include <hip/hip_runtime.h>

// Problem constants (from reference): B=16384, D=255, K=4, L=16, T=1020
constexpr int T_TUN = 1020;
constexpr int D_DST = 255;
constexpr int L_LNK = 16;
constexpr float EPS = 1e-8f;
constexpr int ROWS_PER_BLOCK = 8;   // 4 waves x 2 rows

__device__ __forceinline__ float read_lane_f(float v, int l) {
  return __builtin_bit_cast(float,
      __builtin_amdgcn_readlane(__builtin_bit_cast(int, v), l));
}

__global__ __launch_bounds__(256) void rowloss_kernel(
    const float* __restrict__ pred,     // [B, T]
    const float* __restrict__ demands,  // [B, D]
    const float* __restrict__ cur,      // [B, L]
    const float* __restrict__ caps,     // [L]
    const int*   __restrict__ t2l,      // [T]
    float* __restrict__ partials)       // [gridDim.x]
{
  const int tid  = threadIdx.x;
  const int lane = tid & 63;
  const int w    = tid >> 6;   // wave id 0..3

  // Bin-major per-lane bins: priv[link*64 + lane].
  //  - scatter RMW (b32): bank = lane&31 -> conflict-free (proven R4/R6)
  //  - column reduce via rotated region walk -> 2-way banks only (free)
  __shared__ float priv_all[4][L_LNK * 64];   // 4 KB/wave, 16 KB/block
  __shared__ float wacc[4];
  float* priv = priv_all[w];

  const int b16 = lane & 15;       // this lane's bin for the reduce/stats
  const int g   = lane >> 4;       // lane group 0..3
  const float capinv = 1.0f / (caps[b16] + EPS);

  // Row-invariant scatter offsets: element index = link*64 + lane
  int off[4][4];
  bool dv[4];
#pragma unroll
  for (int j = 0; j < 4; ++j) {
    const int d = lane + 64 * j;
    dv[j] = (d < D_DST);
    const int dd = dv[j] ? d : 0;
    const int4 lk = ((const int4*)t2l)[dd];   // t2l[4d..4d+3]
    off[j][0] = lk.x * 64 + lane;
    off[j][1] = lk.y * 64 + lane;
    off[j][2] = lk.z * 64 + lane;
    off[j][3] = lk.w * 64 + lane;
  }

  const int row0 = blockIdx.x * ROWS_PER_BLOCK + w * 2;

  // ---- issue ALL global loads for both rows up front (max MLP) ----
  float4 r4[2][4];
  float  dm[2][4];
  float  mycur[2];
#pragma unroll
  for (int r = 0; r < 2; ++r) {
    const int b = row0 + r;
    const float4* prow = (const float4*)(pred + (size_t)b * T_TUN);
    const float*  drow = demands + (size_t)b * D_DST;
    mycur[r] = cur[(size_t)b * L_LNK + b16];
#pragma unroll
    for (int j = 0; j < 4; ++j) {
      const int d = lane + 64 * j;
      if (dv[j]) { r4[r][j] = prow[d]; dm[r][j] = drow[d]; }
    }
  }

  float acc = 0.0f;

#pragma unroll
  for (int r = 0; r < 2; ++r) {
    __builtin_amdgcn_wave_barrier();  // keep zero-writes after prior row's reads

    // zero the wave's 1024-float region: 4x ds_write_b128
    {
      const float4 z = make_float4(0.f, 0.f, 0.f, 0.f);
      float4* pz = (float4*)priv;
#pragma unroll
      for (int i = 0; i < 4; ++i) pz[lane + 64 * i] = z;
    }

    // scatter: scalar b32 RMW into lane-distinct slots (conflict-free)
#pragma unroll
    for (int j = 0; j < 4; ++j) {
      if (!dv[j]) continue;            // only lane63/j3 diverges
      const float4 v = r4[r][j];
      const float  d = dm[r][j];
      priv[off[j][0]] += v.x * d;
      priv[off[j][1]] += v.y * d;
      priv[off[j][2]] += v.z * d;
      priv[off[j][3]] += v.w * d;
    }

    __builtin_amdgcn_wave_barrier();  // keep reduce reads after scatter writes

    // column reduce: lane sums its bin over 16 regions (rotated -> 2-way banks)
    float cs = 0.0f;
#pragma unroll
    for (int k = 0; k < 16; ++k)
      cs += priv[b16 * 64 + 16 * g + ((k + b16) & 15)];
    cs += __shfl_xor(cs, 16, 64);
    cs += __shfl_xor(cs, 32, 64);

    const float u = cs * capinv;

    // fused stats: group 0 sums u, 1 sums u^2, 2 sums u*cur, 3 maxes u
    float val = (g == 0) ? u : (g == 1) ? (u * u)
              : (g == 2) ? (u * mycur[r]) : u;
#pragma unroll
    for (int m = 1; m < 16; m <<= 1) {
      const float o  = __shfl_xor(val, m, 64);
      const float sm = val + o;
      const float mm = fmaxf(val, o);
      val = (g == 3) ? mm : sm;
    }
    const float s1 = read_lane_f(val, 0);
    const float s2 = read_lane_f(val, 16);
    const float s3 = read_lane_f(val, 32);
    const float mx = read_lane_f(val, 48);
    const float var = (s2 - s1 * s1 * (1.0f / 16.0f)) * (1.0f / 15.0f); // ddof=1
    acc += 0.3f * var + 0.5f * s3 + 0.2f * mx;
  }

  if (lane == 0) wacc[w] = acc;
  __syncthreads();
  if (tid == 0) partials[blockIdx.x] = wacc[0] + wacc[1] + wacc[2] + wacc[3];
}

__global__ __launch_bounds__(256) void reduce_kernel(
    const float* __restrict__ partials, int n, float* __restrict__ out, float invB)
{
  __shared__ float s[256];
  const int tid = threadIdx.x;
  float a = 0.0f;
  for (int i = tid; i < n; i += 256) a += partials[i];
  s[tid] = a;
  __syncthreads();
  for (int st = 128; st > 0; st >>= 1) {
    if (tid < st) s[tid] += s[tid + st];
    __syncthreads();
  }
  if (tid == 0) out[0] = s[0] * invB;
}

extern "C" void kernel_launch(void* const* d_in, const int* in_sizes, int n_in,
                              void* d_out, int out_size, void* d_ws, size_t ws_size,
                              hipStream_t stream) {
  const float* pred    = (const float*)d_in[0];  // [B, T]
  const float* demands = (const float*)d_in[1];  // [B, D]
  const float* cur     = (const float*)d_in[2];  // [B, L]
  const float* caps    = (const float*)d_in[3];  // [L]
  const int*   t2l     = (const int*)d_in[4];    // [T]
  float* out = (float*)d_out;

  const int L = in_sizes[3];          // 16
  const int B = in_sizes[2] / L;      // 16384

  const int grid = B / ROWS_PER_BLOCK;  // 2048
  float* partials = (float*)d_ws;       // grid floats

  rowloss_kernel<<<grid, 256, 0, stream>>>(pred, demands, cur, caps, t2l, partials);
  reduce_kernel<<<1, 256, 0, stream>>>(partials, grid, out, 1.0f / (float)B);
}

// Round 8
// 107.869 us; speedup vs baseline: 1.8628x; 1.0122x over previous
//
#include <hip/hip_runtime.h>

// Problem constants (from reference): B=16384, D=255, K=4, L=16, T=1020
constexpr int T_TUN = 1020;
constexpr int D_DST = 255;
constexpr int L_LNK = 16;
constexpr float EPS = 1e-8f;
constexpr int ROWS_PER_BLOCK = 8;   // 4 waves x 2 rows

__device__ __forceinline__ float read_lane_f(float v, int l) {
  return __builtin_bit_cast(float,
      __builtin_amdgcn_readlane(__builtin_bit_cast(int, v), l));
}

__global__ __launch_bounds__(256) void rowloss_kernel(
    const float* __restrict__ pred,     // [B, T]
    const float* __restrict__ demands,  // [B, D]
    const float* __restrict__ cur,      // [B, L]
    const float* __restrict__ caps,     // [L]
    const int*   __restrict__ t2l,      // [T]
    float* __restrict__ partials)       // [gridDim.x]
{
  const int tid  = threadIdx.x;
  const int lane = tid & 63;
  const int w    = tid >> 6;   // wave id 0..3

  // Bin-major per-lane bins: priv[link*64 + lane].
  //  - scatter RMW (b32): bank = lane&31 -> conflict-free (proven R4/R6)
  //  - column reduce: lane's 16 copies are CONSECUTIVE -> 4x ds_read_b128
  __shared__ float priv_all[4][L_LNK * 64];   // 4 KB/wave, 16 KB/block
  __shared__ float wacc[4];
  float* priv = priv_all[w];

  const int b16 = lane & 15;       // this lane's bin for the reduce/stats
  const int g   = lane >> 4;       // lane group 0..3
  const float capinv = 1.0f / (caps[b16] + EPS);

  // Row-invariant scatter offsets: element index = link*64 + lane
  int off[4][4];
  bool dv[4];
#pragma unroll
  for (int j = 0; j < 4; ++j) {
    const int d = lane + 64 * j;
    dv[j] = (d < D_DST);
    const int dd = dv[j] ? d : 0;
    const int4 lk = ((const int4*)t2l)[dd];   // t2l[4d..4d+3]
    off[j][0] = lk.x * 64 + lane;
    off[j][1] = lk.y * 64 + lane;
    off[j][2] = lk.z * 64 + lane;
    off[j][3] = lk.w * 64 + lane;
  }

  const int row0 = blockIdx.x * ROWS_PER_BLOCK + w * 2;

  // ---- issue ALL global loads for both rows up front (max MLP) ----
  float4 r4[2][4];
  float  dm[2][4];
  float  mycur[2];
#pragma unroll
  for (int r = 0; r < 2; ++r) {
    const int b = row0 + r;
    const float4* prow = (const float4*)(pred + (size_t)b * T_TUN);
    const float*  drow = demands + (size_t)b * D_DST;
    mycur[r] = cur[(size_t)b * L_LNK + b16];
#pragma unroll
    for (int j = 0; j < 4; ++j) {
      const int d = lane + 64 * j;
      if (dv[j]) { r4[r][j] = prow[d]; dm[r][j] = drow[d]; }
    }
  }

  float acc = 0.0f;

#pragma unroll
  for (int r = 0; r < 2; ++r) {
    __builtin_amdgcn_wave_barrier();  // keep zero-writes after prior row's reads

    // zero the wave's 1024-float region: 4x ds_write_b128
    {
      const float4 z = make_float4(0.f, 0.f, 0.f, 0.f);
      float4* pz = (float4*)priv;
#pragma unroll
      for (int i = 0; i < 4; ++i) pz[lane + 64 * i] = z;
    }

    // scatter: scalar b32 RMW into lane-distinct slots (conflict-free)
#pragma unroll
    for (int j = 0; j < 4; ++j) {
      if (!dv[j]) continue;            // only lane63/j3 diverges
      const float4 v = r4[r][j];
      const float  d = dm[r][j];
      priv[off[j][0]] += v.x * d;
      priv[off[j][1]] += v.y * d;
      priv[off[j][2]] += v.z * d;
      priv[off[j][3]] += v.w * d;
    }

    __builtin_amdgcn_wave_barrier();  // keep reduce reads after scatter writes

    // column reduce: lane's 16 copies (16g..16g+15 of bin b16) = 4x b128
    float cs = 0.0f;
    {
      const float4* pr = (const float4*)(priv + b16 * 64 + 16 * g);
#pragma unroll
      for (int q = 0; q < 4; ++q) {
        const float4 v = pr[q];
        cs += v.x + v.y + v.z + v.w;
      }
    }
    cs += __shfl_xor(cs, 16, 64);
    cs += __shfl_xor(cs, 32, 64);

    const float u = cs * capinv;

    // fused stats: group 0 sums u, 1 sums u^2, 2 sums u*cur, 3 maxes u
    float val = (g == 0) ? u : (g == 1) ? (u * u)
              : (g == 2) ? (u * mycur[r]) : u;
#pragma unroll
    for (int m = 1; m < 16; m <<= 1) {
      const float o  = __shfl_xor(val, m, 64);
      const float sm = val + o;
      const float mm = fmaxf(val, o);
      val = (g == 3) ? mm : sm;
    }
    const float s1 = read_lane_f(val, 0);
    const float s2 = read_lane_f(val, 16);
    const float s3 = read_lane_f(val, 32);
    const float mx = read_lane_f(val, 48);
    const float var = (s2 - s1 * s1 * (1.0f / 16.0f)) * (1.0f / 15.0f); // ddof=1
    acc += 0.3f * var + 0.5f * s3 + 0.2f * mx;
  }

  if (lane == 0) wacc[w] = acc;
  __syncthreads();
  if (tid == 0) partials[blockIdx.x] = wacc[0] + wacc[1] + wacc[2] + wacc[3];
}

__global__ __launch_bounds__(256) void reduce_kernel(
    const float* __restrict__ partials, int n, float* __restrict__ out, float invB)
{
  __shared__ float s[256];
  const int tid = threadIdx.x;
  const float4* p4 = (const float4*)partials;
  const int n4 = n >> 2;
  float a = 0.0f;
  for (int i = tid; i < n4; i += 256) {
    const float4 v = p4[i];
    a += v.x + v.y + v.z + v.w;
  }
  s[tid] = a;
  __syncthreads();
  for (int st = 128; st > 0; st >>= 1) {
    if (tid < st) s[tid] += s[tid + st];
    __syncthreads();
  }
  if (tid == 0) out[0] = s[0] * invB;
}

extern "C" void kernel_launch(void* const* d_in, const int* in_sizes, int n_in,
                              void* d_out, int out_size, void* d_ws, size_t ws_size,
                              hipStream_t stream) {
  const float* pred    = (const float*)d_in[0];  // [B, T]
  const float* demands = (const float*)d_in[1];  // [B, D]
  const float* cur     = (const float*)d_in[2];  // [B, L]
  const float* caps    = (const float*)d_in[3];  // [L]
  const int*   t2l     = (const int*)d_in[4];    // [T]
  float* out = (float*)d_out;

  const int L = in_sizes[3];          // 16
  const int B = in_sizes[2] / L;      // 16384

  const int grid = B / ROWS_PER_BLOCK;  // 2048
  float* partials = (float*)d_ws;       // grid floats

  rowloss_kernel<<<grid, 256, 0, stream>>>(pred, demands, cur, caps, t2l, partials);
  reduce_kernel<<<1, 256, 0, stream>>>(partials, grid, out, 1.0f / (float)B);
}